// Round 5
// baseline (140.738 us; speedup 1.0000x reference)
//
#include <hip/hip_runtime.h>

typedef unsigned short u16;
typedef u16   u16x8 __attribute__((ext_vector_type(8)));
typedef short s16x8 __attribute__((ext_vector_type(8)));
typedef float f32x4 __attribute__((ext_vector_type(4)));

__device__ __forceinline__ float b2f(u16 u) {
    return __uint_as_float(((unsigned)u) << 16);
}
__device__ __forceinline__ u16 f2b(float f) {
    unsigned x = __float_as_uint(f);
    x += 0x7fffu + ((x >> 16) & 1u);
    return (u16)(x >> 16);
}
// async global->LDS, 16B per lane; LDS dest = wave-uniform base + lane*16
__device__ __forceinline__ void gload_lds(const u16* g, u16* l) {
    __builtin_amdgcn_global_load_lds(
        (const __attribute__((address_space(1))) unsigned int*)g,
        (__attribute__((address_space(3))) unsigned int*)l, 16, 0, 0);
}

#define THETA_SCALE 0.05190512648261f   // log2(10000)/256

// ---------------- prep: Xb = bf16(x) + WT = bf16(Wqk^T) + zero kvbuf/ksum ---
__global__ __launch_bounds__(256)
void k_prep(const float* __restrict__ X, u16* __restrict__ Xb,
            const float* __restrict__ W, u16* __restrict__ WT,
            float* __restrict__ kvz) {
    if (blockIdx.x < 4096) {
        size_t i = (size_t)(blockIdx.x * 256 + threadIdx.x) * 8;
        float4 a = *(const float4*)(X + i);
        float4 b = *(const float4*)(X + i + 4);
        u16x8 r;
        r[0] = f2b(a.x); r[1] = f2b(a.y); r[2] = f2b(a.z); r[3] = f2b(a.w);
        r[4] = f2b(b.x); r[5] = f2b(b.y); r[6] = f2b(b.z); r[7] = f2b(b.w);
        *(u16x8*)(Xb + i) = r;
    } else if (blockIdx.x < 4608) {
        __shared__ float tile[32][33];
        int bid = blockIdx.x - 4096;        // 0..511 = 32 x 16
        int c0 = (bid & 31) * 32;
        int r0 = (bid >> 5) * 32;
        int tx = threadIdx.x & 31;
        int ty = threadIdx.x >> 5;
        #pragma unroll
        for (int i = 0; i < 4; ++i) {
            int r = ty + i * 8;
            tile[r][tx] = W[(size_t)(r0 + r) * 1024 + c0 + tx];
        }
        __syncthreads();
        #pragma unroll
        for (int i = 0; i < 4; ++i) {
            int r = ty + i * 8;
            WT[(size_t)(c0 + r) * 512 + r0 + tx] = f2b(tile[tx][r]);
        }
    } else {
        // zero kvbuf (65536 f) + ksum (2048 f): 66 blocks x 1024 floats
        size_t i = (size_t)(blockIdx.x - 4608) * 1024 + threadIdx.x * 4;
        *(float4*)(kvz + i) = make_float4(0.f, 0.f, 0.f, 0.f);
    }
}

// ---------------- GEMM: Xb x WT + bias, elu+1 -> Qb (bf16), Kb (bf16) -------
// 256x256 tile, 8 waves (2M x 4N), BK=64 double-buffered, counted vmcnt(8),
// raw s_barrier (no drain), setprio around MFMA clusters.
// Dispatch-policy-robust XCD remap: by=(lin>>3)&3, bx=(lin&7)|((lin>>5)<<3).
//  - round-robin dispatch (XCD=lin%8): XCD holds bx in {c,c+8,..,c+56}, all by
//  - chunked dispatch (XCD=lin/32):    XCD holds bx in {8q..8q+7}, all by
// Either way: 8 A-panels (2 MB) + WT (1 MB) = 3 MB per-XCD working set -> L2
// reuse of each A-panel x4 and WT x~32.
// LDS XOR-swizzle (both sides): LDS chunk kc of row r holds global chunk kc^(r&7)
__global__ __launch_bounds__(512, 2)
void k_gemm(const u16* __restrict__ Xb, const u16* __restrict__ WT,
            const float* __restrict__ bqk,
            u16* __restrict__ Qb, u16* __restrict__ Kb) {
    __shared__ u16 As[2][256 * 64];      // 64 KB
    __shared__ u16 Bs[2][256 * 64];      // 64 KB
    const int t = threadIdx.x;           // 0..511
    const int lin = blockIdx.x + (blockIdx.y << 6);   // gridDim.x = 64
    const int by = (lin >> 3) & 3;
    const int bx = (lin & 7) | ((lin >> 5) << 3);
    const int m0 = bx * 256;
    const int n0 = by * 256;
    const int lane = t & 63;
    const int wave = t >> 6;             // 0..7
    const int wm = (wave >> 2) * 128;    // 2 m-wave rows
    const int wn = (wave & 3) * 64;      // 4 n-wave cols
    const int quad = lane >> 4;
    const int l16 = lane & 15;
    const int srow = lane >> 3;          // staging: row within wave's 8-row slice
    const int skc  = lane & 7;           // staging: 16B granule within row

    f32x4 acc[8][4];
    #pragma unroll
    for (int i = 0; i < 8; ++i)
        #pragma unroll
        for (int j = 0; j < 4; ++j) acc[i][j] = (f32x4){0.f, 0.f, 0.f, 0.f};

    // prologue: stage K-tile 0 into buffer 0 (8 gloads/wave)
    #pragma unroll
    for (int c = 0; c < 4; ++c) {
        int row = c * 64 + wave * 8 + srow;
        int kcs = (skc ^ (row & 7)) * 8;
        gload_lds(Xb + (size_t)(m0 + row) * 512 + kcs,
                  &As[0][(c * 64 + wave * 8) * 64]);
        gload_lds(WT + (size_t)(n0 + row) * 512 + kcs,
                  &Bs[0][(c * 64 + wave * 8) * 64]);
    }

    for (int kt = 0; kt < 8; ++kt) {
        const int cur = kt & 1;
        if (kt < 7) {
            const int k0 = (kt + 1) * 64;
            #pragma unroll
            for (int c = 0; c < 4; ++c) {
                int row = c * 64 + wave * 8 + srow;
                int kcs = (skc ^ (row & 7)) * 8;
                gload_lds(Xb + (size_t)(m0 + row) * 512 + k0 + kcs,
                          &As[cur ^ 1][(c * 64 + wave * 8) * 64]);
                gload_lds(WT + (size_t)(n0 + row) * 512 + k0 + kcs,
                          &Bs[cur ^ 1][(c * 64 + wave * 8) * 64]);
            }
            // wait for this tile's 8 loads; next tile's 8 stay in flight
            asm volatile("s_waitcnt vmcnt(8)" ::: "memory");
        } else {
            asm volatile("s_waitcnt vmcnt(0)" ::: "memory");
        }
        __builtin_amdgcn_s_barrier();
        asm volatile("" ::: "memory");

        #pragma unroll
        for (int s = 0; s < 2; ++s) {
            const int cb = s * 4 + quad;
            s16x8 af[8], bf[4];
            #pragma unroll
            for (int f = 0; f < 8; ++f) {
                int row = wm + f * 16 + l16;
                af[f] = *(const s16x8*)&As[cur][row * 64 + ((cb ^ (row & 7)) * 8)];
            }
            #pragma unroll
            for (int j = 0; j < 4; ++j) {
                int row = wn + j * 16 + l16;
                bf[j] = *(const s16x8*)&Bs[cur][row * 64 + ((cb ^ (row & 7)) * 8)];
            }
            __builtin_amdgcn_s_setprio(1);
            #pragma unroll
            for (int f = 0; f < 8; ++f)
                #pragma unroll
                for (int j = 0; j < 4; ++j)
                    acc[f][j] = __builtin_amdgcn_mfma_f32_16x16x32_bf16(
                        af[f], bf[j], acc[f][j], 0, 0, 0);
            __builtin_amdgcn_s_setprio(0);
        }
        asm volatile("" ::: "memory");
        __builtin_amdgcn_s_barrier();
    }

    u16* O = (n0 < 512) ? Qb : Kb;   // block-uniform
    #pragma unroll
    for (int f = 0; f < 8; ++f)
        #pragma unroll
        for (int j = 0; j < 4; ++j) {
            int col = n0 + wn + j * 16 + l16;
            float bias = bqk[col];
            int gc = col & 511;
            #pragma unroll
            for (int r = 0; r < 4; ++r) {
                int grow = m0 + wm + f * 16 + quad * 4 + r;
                float v = acc[f][j][r] + bias;
                v = v > 0.f ? v + 1.f : __expf(v);   // elu(v)+1
                O[(size_t)grow * 512 + gc] = f2b(v);
            }
        }
}

// ---------------- kv via MFMA: kv[d][e] += sum_n kr[n,d]*v[n,e] -------------
// per (bh, chunk): 32x32 GEMM, K=512; channel-major LDS with bank rotation;
// 4 waves = 4 quadrants; atomicAdd into shared kvbuf (proven handoff).
__global__ __launch_bounds__(256)
void k_kv(const u16* __restrict__ Kb, const u16* __restrict__ Xb,
          float* __restrict__ kvbuf, float* __restrict__ ksum) {
    const int bh = blockIdx.x;            // 0..63
    const int b = bh >> 4, h = bh & 15;
    const int nb = blockIdx.y * 512;      // N chunk
    __shared__ u16 krT[32 * 72];          // [c][n], stride 72 (144B, 16B-align)
    __shared__ u16 vT[32 * 72];
    __shared__ float red[64 * 36];        // ksum reduce
    const int t = threadIdx.x;
    const int row = t >> 2;               // 0..63 staging row
    const int c8 = (t & 3) * 8;           // staging channel octet
    const int rot_w = 16 * ((c8 >> 3) & 3);   // bank rotation for writes
    const int lane = t & 63;
    const int wave = t >> 6;
    const int quad = lane >> 4;
    const int l16 = lane & 15;
    const int dq = (wave >> 1) * 16;      // d-quadrant base
    const int eq = (wave & 1) * 16;      // e-quadrant base
    const int ca = dq + l16;              // A channel (d)
    const int cb2 = eq + l16;             // B channel (e)
    const int rot_a = 16 * ((ca >> 3) & 3);
    const int rot_b = 16 * ((cb2 >> 3) & 3);

    float ksl[8] = {0, 0, 0, 0, 0, 0, 0, 0};
    f32x4 acc = {0.f, 0.f, 0.f, 0.f};

    float th[4];
    #pragma unroll
    for (int p = 0; p < 4; ++p)
        th[p] = exp2f(-THETA_SCALE * (float)(h * 16 + (c8 >> 1) + p));

    for (int pass = 0; pass < 8; ++pass) {
        int n = nb + pass * 64 + row;
        size_t base = (size_t)(b * 4096 + n) * 512 + h * 32 + c8;
        u16x8 k8 = *(const u16x8*)(Kb + base);
        u16x8 v8 = *(const u16x8*)(Xb + base);
        float kf[8], kr[8];
        #pragma unroll
        for (int j = 0; j < 8; ++j) kf[j] = b2f(k8[j]);
        #pragma unroll
        for (int p = 0; p < 4; ++p) {
            float sv, cv;
            sincosf((float)n * th[p], &sv, &cv);
            kr[2 * p]     = kf[2 * p] * cv - kf[2 * p + 1] * sv;
            kr[2 * p + 1] = kf[2 * p] * sv + kf[2 * p + 1] * cv;
        }
        #pragma unroll
        for (int j = 0; j < 8; ++j) ksl[j] += kf[j];
        if (pass) __syncthreads();
        int colw = (row + rot_w) & 63;    // rotated column
        #pragma unroll
        for (int j = 0; j < 8; ++j) {
            krT[(c8 + j) * 72 + colw] = f2b(kr[j]);
            vT[(c8 + j) * 72 + colw] = v8[j];
        }
        __syncthreads();
        #pragma unroll
        for (int ks = 0; ks < 64; ks += 32) {
            s16x8 a4 = *(const s16x8*)&krT[ca * 72 + ((ks + quad * 8 + rot_a) & 63)];
            s16x8 b4 = *(const s16x8*)&vT[cb2 * 72 + ((ks + quad * 8 + rot_b) & 63)];
            acc = __builtin_amdgcn_mfma_f32_16x16x32_bf16(a4, b4, acc, 0, 0, 0);
        }
    }

    // kv: D layout col=e=l16, row=d=quad*4+r ; device-scope atomic handoff
    #pragma unroll
    for (int r = 0; r < 4; ++r)
        atomicAdd(&kvbuf[(size_t)bh * 1024 + (dq + quad * 4 + r) * 32 + eq + l16],
                  acc[r]);

    // ksum reduce
    __syncthreads();
    *(float4*)&red[row * 36 + c8]     = make_float4(ksl[0], ksl[1], ksl[2], ksl[3]);
    *(float4*)&red[row * 36 + c8 + 4] = make_float4(ksl[4], ksl[5], ksl[6], ksl[7]);
    __syncthreads();
    if (t < 32) {
        float s = 0.f;
        for (int r = 0; r < 64; ++r) s += red[r * 36 + t];
        atomicAdd(&ksum[bh * 32 + t], s);
    }
}

// ---------------- out = z * (q_rope @ kv)/N + lepe (f32 to d_out) -----------
// phase 2 via MFMA: out[64x32] = qr[64x32] @ kv[32x32]; A = qr_s[row][d] bf16,
// B = kvT_s[e][d] bf16 (same [n][k] B-operand layout as the proven gemm);
// C round-trips LDS so the row-major lepe epilogue stays unchanged.
__global__ __launch_bounds__(256)
void k_out(const u16* __restrict__ Qb, const u16* __restrict__ Xb,
           const float* __restrict__ kvbuf, const float* __restrict__ ksum,
           const float* __restrict__ lw, const float* __restrict__ lb,
           float* __restrict__ OUT) {
    const int b = blockIdx.x >> 6;
    const int nb = (blockIdx.x & 63) * 64;
    const int hbase = blockIdx.y * 4;
    __shared__ u16 kvT_s[32 * 36];     // [e][d] bf16, stride 36
    __shared__ u16 qr_s[64 * 36];      // [row][d] bf16, stride 36
    __shared__ float out_s[64 * 36];   // [row][e] f32, stride 36
    __shared__ float ks_s[32];
    __shared__ float z_s[64];
    const int t = threadIdx.x;
    const int row = t >> 2;          // 0..63 local n
    const int c4 = t & 3;
    const int e0 = c4 * 8;
    const int lane = t & 63;
    const int wave = t >> 6;
    const int quad = lane >> 4;
    const int l16 = lane & 15;
    const float invN = 1.f / 4096.f;
    const int n = nb + row;
    const size_t rowbase = (size_t)(b * 4096 + n) * 512;

    for (int hh = 0; hh < 4; ++hh) {
        const int h = hbase + hh;
        const int bh = b * 16 + h;
        if (hh) __syncthreads();               // prev iteration LDS reads done
        // stage kvT (bf16, transposed) + kmean
        {
            int id = t * 4;                    // 0..1023, e varies fastest
            float4 kvv = *(const float4*)&kvbuf[(size_t)bh * 1024 + id];
            int d = id >> 5, e = id & 31;
            kvT_s[(e + 0) * 36 + d] = f2b(kvv.x * invN);
            kvT_s[(e + 1) * 36 + d] = f2b(kvv.y * invN);
            kvT_s[(e + 2) * 36 + d] = f2b(kvv.z * invN);
            kvT_s[(e + 3) * 36 + d] = f2b(kvv.w * invN);
        }
        if (t < 32) ks_s[t] = ksum[bh * 32 + t] * invN;
        __syncthreads();

        // phase 1: q (bf16), z partial dot, rope, stage qr bf16
        u16x8 q8 = *(const u16x8*)(Qb + rowbase + h * 32 + e0);
        float qf[8];
        #pragma unroll
        for (int j = 0; j < 8; ++j) qf[j] = b2f(q8[j]);
        float part = 0.f;
        #pragma unroll
        for (int j = 0; j < 8; ++j) part += qf[j] * ks_s[e0 + j];
        u16x8 qr8;
        #pragma unroll
        for (int p = 0; p < 4; ++p) {
            float th = exp2f(-THETA_SCALE * (float)(h * 16 + c4 * 4 + p));
            float sv, cv;
            sincosf((float)n * th, &sv, &cv);
            qr8[2 * p]     = f2b(qf[2 * p] * cv - qf[2 * p + 1] * sv);
            qr8[2 * p + 1] = f2b(qf[2 * p] * sv + qf[2 * p + 1] * cv);
        }
        *(u16x8*)&qr_s[row * 36 + e0] = qr8;
        part += __shfl_xor(part, 1);
        part += __shfl_xor(part, 2);
        if (c4 == 0) z_s[row] = 1.f / (part + 1e-6f);
        __syncthreads();

        // phase 2 (MFMA): wave = 16-row tile; 2 e-tiles; K=32 in one step
        {
            f32x4 zero4 = {0.f, 0.f, 0.f, 0.f};
            s16x8 a4 = *(const s16x8*)&qr_s[(wave * 16 + l16) * 36 + quad * 8];
            #pragma unroll
            for (int et = 0; et < 2; ++et) {
                s16x8 b4 = *(const s16x8*)&kvT_s[(et * 16 + l16) * 36 + quad * 8];
                f32x4 cacc = __builtin_amdgcn_mfma_f32_16x16x32_bf16(
                    a4, b4, zero4, 0, 0, 0);
                #pragma unroll
                for (int r = 0; r < 4; ++r)
                    out_s[(wave * 16 + quad * 4 + r) * 36 + et * 16 + l16] = cacc[r];
            }
        }
        __syncthreads();

        // epilogue: read out_s row-major, z scale + lepe + store f32
        const float z = z_s[row];
        float4 o0 = *(const float4*)&out_s[row * 36 + e0];
        float4 o1 = *(const float4*)&out_s[row * 36 + e0 + 4];
        float o[8] = {o0.x, o0.y, o0.z, o0.w, o1.x, o1.y, o1.z, o1.w};
        const int cb = h * 32 + e0;
        u16x8 xc = *(const u16x8*)(Xb + rowbase + cb);
        u16x8 xm = {0, 0, 0, 0, 0, 0, 0, 0};
        u16x8 xp = {0, 0, 0, 0, 0, 0, 0, 0};
        if (n > 0)    xm = *(const u16x8*)(Xb + rowbase - 512 + cb);
        if (n < 4095) xp = *(const u16x8*)(Xb + rowbase + 512 + cb);
        float rv[8];
        #pragma unroll
        for (int j = 0; j < 8; ++j) {
            int c = cb + j;
            float lep = b2f(xm[j]) * lw[c * 3] +
                        b2f(xc[j]) * lw[c * 3 + 1] +
                        b2f(xp[j]) * lw[c * 3 + 2] + lb[c];
            rv[j] = o[j] * z + lep;
        }
        float* Of = OUT + rowbase + cb;
        *(float4*)Of       = make_float4(rv[0], rv[1], rv[2], rv[3]);
        *(float4*)(Of + 4) = make_float4(rv[4], rv[5], rv[6], rv[7]);
    }
}

extern "C" void kernel_launch(void* const* d_in, const int* in_sizes, int n_in,
                              void* d_out, int out_size, void* d_ws, size_t ws_size,
                              hipStream_t stream) {
    const float* x   = (const float*)d_in[0];
    const float* Wqk = (const float*)d_in[1];
    const float* bqk = (const float*)d_in[2];
    const float* lw  = (const float*)d_in[3];
    const float* lb  = (const float*)d_in[4];
    float* out = (float*)d_out;

    // workspace (~49.3 MB); kvbuf+ksum contiguous (zeroed by k_prep tail)
    char* w = (char*)d_ws;
    u16* Kb      = (u16*)w;   w += (size_t)16384 * 512 * 2;   // 16 MB
    u16* Qb      = (u16*)w;   w += (size_t)16384 * 512 * 2;   // 16 MB
    u16* Xb      = (u16*)w;   w += (size_t)16384 * 512 * 2;   // 16 MB
    u16* WT      = (u16*)w;   w += (size_t)1024 * 512 * 2;    // 1 MB
    float* kvbuf = (float*)w; w += (size_t)64 * 1024 * 4;     // 256 KB
    float* ksum  = (float*)w;                                 // 8 KB (contig)

    k_prep<<<4674, 256, 0, stream>>>(x, Xb, Wqk, WT, kvbuf);
    k_gemm<<<dim3(64, 4), 512, 0, stream>>>(Xb, WT, bqk, Qb, Kb);
    k_kv<<<dim3(64, 8), 256, 0, stream>>>(Kb, Xb, kvbuf, ksum);
    k_out<<<dim3(256, 4), 256, 0, stream>>>(Qb, Xb, kvbuf, ksum, lw, lb, out);
}

// Round 6
// 139.778 us; speedup vs baseline: 1.0069x; 1.0069x over previous
//
#include <hip/hip_runtime.h>

typedef unsigned short u16;
typedef u16   u16x8 __attribute__((ext_vector_type(8)));
typedef short s16x8 __attribute__((ext_vector_type(8)));
typedef float f32x4 __attribute__((ext_vector_type(4)));

__device__ __forceinline__ float b2f(u16 u) {
    return __uint_as_float(((unsigned)u) << 16);
}
__device__ __forceinline__ u16 f2b(float f) {
    unsigned x = __float_as_uint(f);
    x += 0x7fffu + ((x >> 16) & 1u);
    return (u16)(x >> 16);
}
// async global->LDS, 16B per lane; LDS dest = wave-uniform base + lane*16
__device__ __forceinline__ void gload_lds(const u16* g, u16* l) {
    __builtin_amdgcn_global_load_lds(
        (const __attribute__((address_space(1))) unsigned int*)g,
        (__attribute__((address_space(3))) unsigned int*)l, 16, 0, 0);
}

#define THETA_SCALE 0.05190512648261f   // log2(10000)/256

// ---------------- prep: Xb = bf16(x) + WT = bf16(Wqk^T) + zero kvbuf/ksum ---
__global__ __launch_bounds__(256)
void k_prep(const float* __restrict__ X, u16* __restrict__ Xb,
            const float* __restrict__ W, u16* __restrict__ WT,
            float* __restrict__ kvz) {
    if (blockIdx.x < 4096) {
        size_t i = (size_t)(blockIdx.x * 256 + threadIdx.x) * 8;
        float4 a = *(const float4*)(X + i);
        float4 b = *(const float4*)(X + i + 4);
        u16x8 r;
        r[0] = f2b(a.x); r[1] = f2b(a.y); r[2] = f2b(a.z); r[3] = f2b(a.w);
        r[4] = f2b(b.x); r[5] = f2b(b.y); r[6] = f2b(b.z); r[7] = f2b(b.w);
        *(u16x8*)(Xb + i) = r;
    } else if (blockIdx.x < 4608) {
        __shared__ float tile[32][33];
        int bid = blockIdx.x - 4096;        // 0..511 = 32 x 16
        int c0 = (bid & 31) * 32;
        int r0 = (bid >> 5) * 32;
        int tx = threadIdx.x & 31;
        int ty = threadIdx.x >> 5;
        #pragma unroll
        for (int i = 0; i < 4; ++i) {
            int r = ty + i * 8;
            tile[r][tx] = W[(size_t)(r0 + r) * 1024 + c0 + tx];
        }
        __syncthreads();
        #pragma unroll
        for (int i = 0; i < 4; ++i) {
            int r = ty + i * 8;
            WT[(size_t)(c0 + r) * 512 + r0 + tx] = f2b(tile[tx][r]);
        }
    } else {
        // zero kvbuf (65536 f) + ksum (2048 f): 66 blocks x 1024 floats
        size_t i = (size_t)(blockIdx.x - 4608) * 1024 + threadIdx.x * 4;
        *(float4*)(kvz + i) = make_float4(0.f, 0.f, 0.f, 0.f);
    }
}

// ---------------- GEMM: Xb x WT + bias, elu+1 -> Qb (bf16), Kb (bf16) -------
// 256x256 tile, 8 waves (2M x 4N), BK=64 double-buffered, counted vmcnt(8),
// raw s_barrier (no drain), setprio around MFMA clusters.
// Dispatch-policy-robust XCD remap (neutral but harmless; L3 absorbs re-reads).
// LDS XOR-swizzle (both sides): LDS chunk kc of row r holds global chunk kc^(r&7)
__global__ __launch_bounds__(512, 2)
void k_gemm(const u16* __restrict__ Xb, const u16* __restrict__ WT,
            const float* __restrict__ bqk,
            u16* __restrict__ Qb, u16* __restrict__ Kb) {
    __shared__ u16 As[2][256 * 64];      // 64 KB
    __shared__ u16 Bs[2][256 * 64];      // 64 KB
    const int t = threadIdx.x;           // 0..511
    const int lin = blockIdx.x + (blockIdx.y << 6);   // gridDim.x = 64
    const int by = (lin >> 3) & 3;
    const int bx = (lin & 7) | ((lin >> 5) << 3);
    const int m0 = bx * 256;
    const int n0 = by * 256;
    const int lane = t & 63;
    const int wave = t >> 6;             // 0..7
    const int wm = (wave >> 2) * 128;    // 2 m-wave rows
    const int wn = (wave & 3) * 64;      // 4 n-wave cols
    const int quad = lane >> 4;
    const int l16 = lane & 15;
    const int srow = lane >> 3;          // staging: row within wave's 8-row slice
    const int skc  = lane & 7;           // staging: 16B granule within row

    f32x4 acc[8][4];
    #pragma unroll
    for (int i = 0; i < 8; ++i)
        #pragma unroll
        for (int j = 0; j < 4; ++j) acc[i][j] = (f32x4){0.f, 0.f, 0.f, 0.f};

    // prologue: stage K-tile 0 into buffer 0 (8 gloads/wave)
    #pragma unroll
    for (int c = 0; c < 4; ++c) {
        int row = c * 64 + wave * 8 + srow;
        int kcs = (skc ^ (row & 7)) * 8;
        gload_lds(Xb + (size_t)(m0 + row) * 512 + kcs,
                  &As[0][(c * 64 + wave * 8) * 64]);
        gload_lds(WT + (size_t)(n0 + row) * 512 + kcs,
                  &Bs[0][(c * 64 + wave * 8) * 64]);
    }

    for (int kt = 0; kt < 8; ++kt) {
        const int cur = kt & 1;
        if (kt < 7) {
            const int k0 = (kt + 1) * 64;
            #pragma unroll
            for (int c = 0; c < 4; ++c) {
                int row = c * 64 + wave * 8 + srow;
                int kcs = (skc ^ (row & 7)) * 8;
                gload_lds(Xb + (size_t)(m0 + row) * 512 + k0 + kcs,
                          &As[cur ^ 1][(c * 64 + wave * 8) * 64]);
                gload_lds(WT + (size_t)(n0 + row) * 512 + k0 + kcs,
                          &Bs[cur ^ 1][(c * 64 + wave * 8) * 64]);
            }
            // wait for this tile's 8 loads; next tile's 8 stay in flight
            asm volatile("s_waitcnt vmcnt(8)" ::: "memory");
        } else {
            asm volatile("s_waitcnt vmcnt(0)" ::: "memory");
        }
        __builtin_amdgcn_s_barrier();
        asm volatile("" ::: "memory");

        #pragma unroll
        for (int s = 0; s < 2; ++s) {
            const int cb = s * 4 + quad;
            s16x8 af[8], bf[4];
            #pragma unroll
            for (int f = 0; f < 8; ++f) {
                int row = wm + f * 16 + l16;
                af[f] = *(const s16x8*)&As[cur][row * 64 + ((cb ^ (row & 7)) * 8)];
            }
            #pragma unroll
            for (int j = 0; j < 4; ++j) {
                int row = wn + j * 16 + l16;
                bf[j] = *(const s16x8*)&Bs[cur][row * 64 + ((cb ^ (row & 7)) * 8)];
            }
            __builtin_amdgcn_s_setprio(1);
            #pragma unroll
            for (int f = 0; f < 8; ++f)
                #pragma unroll
                for (int j = 0; j < 4; ++j)
                    acc[f][j] = __builtin_amdgcn_mfma_f32_16x16x32_bf16(
                        af[f], bf[j], acc[f][j], 0, 0, 0);
            __builtin_amdgcn_s_setprio(0);
        }
        asm volatile("" ::: "memory");
        __builtin_amdgcn_s_barrier();
    }

    u16* O = (n0 < 512) ? Qb : Kb;   // block-uniform
    #pragma unroll
    for (int f = 0; f < 8; ++f)
        #pragma unroll
        for (int j = 0; j < 4; ++j) {
            int col = n0 + wn + j * 16 + l16;
            float bias = bqk[col];
            int gc = col & 511;
            #pragma unroll
            for (int r = 0; r < 4; ++r) {
                int grow = m0 + wm + f * 16 + quad * 4 + r;
                float v = acc[f][j][r] + bias;
                v = v > 0.f ? v + 1.f : __expf(v);   // elu(v)+1
                O[(size_t)grow * 512 + gc] = f2b(v);
            }
        }
}

// ---------------- kv via MFMA: kv[d][e] += sum_n kr[n,d]*v[n,e] -------------
// per (bh, chunk): 32x32 GEMM, K=512; channel-major LDS with bank rotation;
// 4 waves = 4 quadrants; atomicAdd into shared kvbuf (proven handoff).
// Software pipeline: pass+1's k8/v8 issued before processing pass, so the
// L2/L3 load latency hides under rope + LDS staging + MFMA of the prior pass.
__global__ __launch_bounds__(256)
void k_kv(const u16* __restrict__ Kb, const u16* __restrict__ Xb,
          float* __restrict__ kvbuf, float* __restrict__ ksum) {
    const int bh = blockIdx.x;            // 0..63
    const int b = bh >> 4, h = bh & 15;
    const int nb = blockIdx.y * 512;      // N chunk
    __shared__ u16 krT[32 * 72];          // [c][n], stride 72 (144B, 16B-align)
    __shared__ u16 vT[32 * 72];
    __shared__ float red[64 * 36];        // ksum reduce
    const int t = threadIdx.x;
    const int row = t >> 2;               // 0..63 staging row
    const int c8 = (t & 3) * 8;           // staging channel octet
    const int rot_w = 16 * ((c8 >> 3) & 3);   // bank rotation for writes
    const int lane = t & 63;
    const int wave = t >> 6;
    const int quad = lane >> 4;
    const int l16 = lane & 15;
    const int dq = (wave >> 1) * 16;      // d-quadrant base
    const int eq = (wave & 1) * 16;      // e-quadrant base
    const int ca = dq + l16;              // A channel (d)
    const int cb2 = eq + l16;             // B channel (e)
    const int rot_a = 16 * ((ca >> 3) & 3);
    const int rot_b = 16 * ((cb2 >> 3) & 3);

    float ksl[8] = {0, 0, 0, 0, 0, 0, 0, 0};
    f32x4 acc = {0.f, 0.f, 0.f, 0.f};

    float th[4];
    #pragma unroll
    for (int p = 0; p < 4; ++p)
        th[p] = exp2f(-THETA_SCALE * (float)(h * 16 + (c8 >> 1) + p));

    // prologue prefetch (pass 0)
    size_t base0 = (size_t)(b * 4096 + nb + row) * 512 + h * 32 + c8;
    u16x8 k8 = *(const u16x8*)(Kb + base0);
    u16x8 v8 = *(const u16x8*)(Xb + base0);

    for (int pass = 0; pass < 8; ++pass) {
        int n = nb + pass * 64 + row;
        u16x8 k8n, v8n;
        if (pass < 7) {
            size_t basen = (size_t)(b * 4096 + n + 64) * 512 + h * 32 + c8;
            k8n = *(const u16x8*)(Kb + basen);
            v8n = *(const u16x8*)(Xb + basen);
        }
        float kf[8], kr[8];
        #pragma unroll
        for (int j = 0; j < 8; ++j) kf[j] = b2f(k8[j]);
        #pragma unroll
        for (int p = 0; p < 4; ++p) {
            float sv, cv;
            sincosf((float)n * th[p], &sv, &cv);
            kr[2 * p]     = kf[2 * p] * cv - kf[2 * p + 1] * sv;
            kr[2 * p + 1] = kf[2 * p] * sv + kf[2 * p + 1] * cv;
        }
        #pragma unroll
        for (int j = 0; j < 8; ++j) ksl[j] += kf[j];
        if (pass) __syncthreads();
        int colw = (row + rot_w) & 63;    // rotated column
        #pragma unroll
        for (int j = 0; j < 8; ++j) {
            krT[(c8 + j) * 72 + colw] = f2b(kr[j]);
            vT[(c8 + j) * 72 + colw] = v8[j];
        }
        __syncthreads();
        #pragma unroll
        for (int ks = 0; ks < 64; ks += 32) {
            s16x8 a4 = *(const s16x8*)&krT[ca * 72 + ((ks + quad * 8 + rot_a) & 63)];
            s16x8 b4 = *(const s16x8*)&vT[cb2 * 72 + ((ks + quad * 8 + rot_b) & 63)];
            acc = __builtin_amdgcn_mfma_f32_16x16x32_bf16(a4, b4, acc, 0, 0, 0);
        }
        k8 = k8n; v8 = v8n;
    }

    // kv: D layout col=e=l16, row=d=quad*4+r ; device-scope atomic handoff
    #pragma unroll
    for (int r = 0; r < 4; ++r)
        atomicAdd(&kvbuf[(size_t)bh * 1024 + (dq + quad * 4 + r) * 32 + eq + l16],
                  acc[r]);

    // ksum reduce
    __syncthreads();
    *(float4*)&red[row * 36 + c8]     = make_float4(ksl[0], ksl[1], ksl[2], ksl[3]);
    *(float4*)&red[row * 36 + c8 + 4] = make_float4(ksl[4], ksl[5], ksl[6], ksl[7]);
    __syncthreads();
    if (t < 32) {
        float s = 0.f;
        for (int r = 0; r < 64; ++r) s += red[r * 36 + t];
        atomicAdd(&ksum[bh * 32 + t], s);
    }
}

// ---------------- out = z * (q_rope @ kv)/N + lepe (f32 to d_out) -----------
// phase 2 via MFMA: out[64x32] = qr[64x32] @ kv[32x32]; A = qr_s[row][d] bf16,
// B = kvT_s[e][d] bf16; C round-trips LDS for the row-major lepe epilogue.
// Latency fixes: cross-iteration prefetch of kvv/ksum/q8; xc/xm/xp + lepe
// weights loaded early (before phase-2 barrier, used in epilogue); lepe
// weights vectorized (6+2 float4 instead of 32 scalar loads).
__global__ __launch_bounds__(256)
void k_out(const u16* __restrict__ Qb, const u16* __restrict__ Xb,
           const float* __restrict__ kvbuf, const float* __restrict__ ksum,
           const float* __restrict__ lw, const float* __restrict__ lb,
           float* __restrict__ OUT) {
    const int b = blockIdx.x >> 6;
    const int nb = (blockIdx.x & 63) * 64;
    const int hbase = blockIdx.y * 4;
    __shared__ u16 kvT_s[32 * 36];     // [e][d] bf16, stride 36
    __shared__ u16 qr_s[64 * 36];      // [row][d] bf16, stride 36
    __shared__ float out_s[64 * 36];   // [row][e] f32, stride 36
    __shared__ float ks_s[32];
    __shared__ float z_s[64];
    const int t = threadIdx.x;
    const int row = t >> 2;          // 0..63 local n
    const int c4 = t & 3;
    const int e0 = c4 * 8;
    const int lane = t & 63;
    const int wave = t >> 6;
    const int quad = lane >> 4;
    const int l16 = lane & 15;
    const float invN = 1.f / 4096.f;
    const int n = nb + row;
    const size_t rowbase = (size_t)(b * 4096 + n) * 512;

    // prologue prefetch (hh = 0)
    float4 kvv = *(const float4*)&kvbuf[(size_t)(b * 16 + hbase) * 1024 + t * 4];
    float ksv = (t < 32) ? ksum[(b * 16 + hbase) * 32 + t] : 0.f;
    u16x8 q8 = *(const u16x8*)(Qb + rowbase + hbase * 32 + e0);

    for (int hh = 0; hh < 4; ++hh) {
        const int h = hbase + hh;
        const int bh = b * 16 + h;
        if (hh) __syncthreads();               // prev iteration LDS reads done
        // stage kvT (bf16, transposed) + kmean, from prefetched kvv/ksv
        {
            int id = t * 4;                    // 0..1023, e varies fastest
            int d = id >> 5, e = id & 31;
            kvT_s[(e + 0) * 36 + d] = f2b(kvv.x * invN);
            kvT_s[(e + 1) * 36 + d] = f2b(kvv.y * invN);
            kvT_s[(e + 2) * 36 + d] = f2b(kvv.z * invN);
            kvT_s[(e + 3) * 36 + d] = f2b(kvv.w * invN);
        }
        if (t < 32) ks_s[t] = ksv * invN;
        __syncthreads();

        // phase 1: q (prefetched), z partial dot, rope, stage qr bf16
        float qf[8];
        #pragma unroll
        for (int j = 0; j < 8; ++j) qf[j] = b2f(q8[j]);
        float part = 0.f;
        #pragma unroll
        for (int j = 0; j < 8; ++j) part += qf[j] * ks_s[e0 + j];
        u16x8 qr8;
        #pragma unroll
        for (int p = 0; p < 4; ++p) {
            float th = exp2f(-THETA_SCALE * (float)(h * 16 + c4 * 4 + p));
            float sv, cv;
            sincosf((float)n * th, &sv, &cv);
            qr8[2 * p]     = f2b(qf[2 * p] * cv - qf[2 * p + 1] * sv);
            qr8[2 * p + 1] = f2b(qf[2 * p] * sv + qf[2 * p + 1] * cv);
        }
        *(u16x8*)&qr_s[row * 36 + e0] = qr8;
        part += __shfl_xor(part, 1);
        part += __shfl_xor(part, 2);
        if (c4 == 0) z_s[row] = 1.f / (part + 1e-6f);

        // ---- early loads for THIS hh's epilogue (hidden under phase 2) ----
        const int cb = h * 32 + e0;
        u16x8 xc = *(const u16x8*)(Xb + rowbase + cb);
        u16x8 xm = {0, 0, 0, 0, 0, 0, 0, 0};
        u16x8 xp = {0, 0, 0, 0, 0, 0, 0, 0};
        if (n > 0)    xm = *(const u16x8*)(Xb + rowbase - 512 + cb);
        if (n < 4095) xp = *(const u16x8*)(Xb + rowbase + 512 + cb);
        float wv[24];
        #pragma unroll
        for (int q = 0; q < 6; ++q)
            *(float4*)&wv[q * 4] = *(const float4*)(lw + cb * 3 + q * 4);
        float lbv[8];
        *(float4*)&lbv[0] = *(const float4*)(lb + cb);
        *(float4*)&lbv[4] = *(const float4*)(lb + cb + 4);
        // ---- cross-iteration prefetch for hh+1 ----
        if (hh < 3) {
            kvv = *(const float4*)&kvbuf[(size_t)(bh + 1) * 1024 + t * 4];
            if (t < 32) ksv = ksum[(bh + 1) * 32 + t];
            q8 = *(const u16x8*)(Qb + rowbase + (h + 1) * 32 + e0);
        }
        __syncthreads();

        // phase 2 (MFMA): wave = 16-row tile; 2 e-tiles; K=32 in one step
        {
            f32x4 zero4 = {0.f, 0.f, 0.f, 0.f};
            s16x8 a4 = *(const s16x8*)&qr_s[(wave * 16 + l16) * 36 + quad * 8];
            #pragma unroll
            for (int et = 0; et < 2; ++et) {
                s16x8 b4 = *(const s16x8*)&kvT_s[(et * 16 + l16) * 36 + quad * 8];
                f32x4 cacc = __builtin_amdgcn_mfma_f32_16x16x32_bf16(
                    a4, b4, zero4, 0, 0, 0);
                #pragma unroll
                for (int r = 0; r < 4; ++r)
                    out_s[(wave * 16 + quad * 4 + r) * 36 + et * 16 + l16] = cacc[r];
            }
        }
        __syncthreads();

        // epilogue: read out_s row-major, z scale + lepe + store f32
        const float z = z_s[row];
        float4 o0 = *(const float4*)&out_s[row * 36 + e0];
        float4 o1 = *(const float4*)&out_s[row * 36 + e0 + 4];
        float o[8] = {o0.x, o0.y, o0.z, o0.w, o1.x, o1.y, o1.z, o1.w};
        float rv[8];
        #pragma unroll
        for (int j = 0; j < 8; ++j) {
            float lep = b2f(xm[j]) * wv[3 * j] +
                        b2f(xc[j]) * wv[3 * j + 1] +
                        b2f(xp[j]) * wv[3 * j + 2] + lbv[j];
            rv[j] = o[j] * z + lep;
        }
        float* Of = OUT + rowbase + cb;
        *(float4*)Of       = make_float4(rv[0], rv[1], rv[2], rv[3]);
        *(float4*)(Of + 4) = make_float4(rv[4], rv[5], rv[6], rv[7]);
    }
}

extern "C" void kernel_launch(void* const* d_in, const int* in_sizes, int n_in,
                              void* d_out, int out_size, void* d_ws, size_t ws_size,
                              hipStream_t stream) {
    const float* x   = (const float*)d_in[0];
    const float* Wqk = (const float*)d_in[1];
    const float* bqk = (const float*)d_in[2];
    const float* lw  = (const float*)d_in[3];
    const float* lb  = (const float*)d_in[4];
    float* out = (float*)d_out;

    // workspace (~49.3 MB); kvbuf+ksum contiguous (zeroed by k_prep tail)
    char* w = (char*)d_ws;
    u16* Kb      = (u16*)w;   w += (size_t)16384 * 512 * 2;   // 16 MB
    u16* Qb      = (u16*)w;   w += (size_t)16384 * 512 * 2;   // 16 MB
    u16* Xb      = (u16*)w;   w += (size_t)16384 * 512 * 2;   // 16 MB
    u16* WT      = (u16*)w;   w += (size_t)1024 * 512 * 2;    // 1 MB
    float* kvbuf = (float*)w; w += (size_t)64 * 1024 * 4;     // 256 KB
    float* ksum  = (float*)w;                                 // 8 KB (contig)

    k_prep<<<4674, 256, 0, stream>>>(x, Xb, Wqk, WT, kvbuf);
    k_gemm<<<dim3(64, 4), 512, 0, stream>>>(Xb, WT, bqk, Qb, Kb);
    k_kv<<<dim3(64, 8), 256, 0, stream>>>(Kb, Xb, kvbuf, ksum);
    k_out<<<dim3(256, 4), 256, 0, stream>>>(Qb, Xb, kvbuf, ksum, lw, lb, out);
}